// Round 3
// baseline (822.389 us; speedup 1.0000x reference)
//
#include <hip/hip_runtime.h>
#include <math.h>

#define HID 1024
#define FF  2048
#define NE  8
#define NT  8192

typedef __attribute__((ext_vector_type(4))) float f32x4;
typedef __bf16 bf16x8 __attribute__((ext_vector_type(8)));

static __device__ __forceinline__ ushort f2b(float f){
  union { float f; unsigned int u; } v; v.f = f;
  unsigned int r = (v.u + 0x7FFFu + ((v.u >> 16) & 1u)) >> 16;
  return (ushort)r;
}

// -------- x (fp32) -> bf16 xb --------
__global__ __launch_bounds__(256) void k_cvt_x(const float* __restrict__ x,
                                               ushort* __restrict__ xb){
  size_t i8 = ((size_t)blockIdx.x * 256 + threadIdx.x) * 8;
  const float* s = x + i8;
  ushort o[8];
  #pragma unroll
  for (int j = 0; j < 8; ++j) o[j] = f2b(s[j]);
  *(uint4*)(xb + i8) = *(uint4*)o;
}

// -------- 64x64 tile transpose + fp32->bf16: src[e][K][N] -> dst[e][N][K] --------
__global__ __launch_bounds__(256) void k_transpose(
    const float* __restrict__ src, ushort* __restrict__ dst, int K, int N){
  __shared__ __align__(16) ushort Tt[64][72];
  int e = blockIdx.z;
  int n0 = blockIdx.x * 64, k0 = blockIdx.y * 64;
  int t = threadIdx.x;
  int r = t >> 2, c = (t & 3) * 16;
  const float* s = src + (size_t)e*K*N + (size_t)(k0+r)*N + n0 + c;
  #pragma unroll
  for (int q = 0; q < 4; ++q){
    float4 v = *(const float4*)(s + q*4);
    Tt[r][c+q*4+0] = f2b(v.x); Tt[r][c+q*4+1] = f2b(v.y);
    Tt[r][c+q*4+2] = f2b(v.z); Tt[r][c+q*4+3] = f2b(v.w);
  }
  __syncthreads();
  ushort tmp[16];
  #pragma unroll
  for (int i = 0; i < 16; ++i) tmp[i] = Tt[c+i][r];
  ushort* d = dst + (size_t)e*N*K + (size_t)(n0+r)*K + k0 + c;
  *(uint4*)(d)     = *(uint4*)&tmp[0];
  *(uint4*)(d + 8) = *(uint4*)&tmp[8];
}

// -------- Router (fp32 inputs, fp64 accumulation): logits -> softmax -> top2 -> softmax(top2 probs)
__global__ __launch_bounds__(256) void k_router(
    const float* __restrict__ x, const float* __restrict__ Wr,
    const float* __restrict__ br, int* __restrict__ topi,
    float* __restrict__ topw, int* __restrict__ counts){
  __shared__ __align__(16) float sW[HID*NE];   // 32 KB
  int tid = threadIdx.x;
  const uint4* srcW = (const uint4*)Wr;
  uint4* dstW = (uint4*)sW;
  #pragma unroll
  for (int i = 0; i < 8; ++i) dstW[tid*8+i] = srcW[tid*8+i];
  __syncthreads();
  int wave = tid >> 6, lane = tid & 63;
  int t = blockIdx.x * 4 + wave;
  const float* xrow = x + (size_t)t * HID;
  double acc[NE];
  #pragma unroll
  for (int e=0;e<NE;++e) acc[e]=0.0;
  for (int it = 0; it < HID/64; ++it){
    int h = it*64 + lane;
    double xv = (double)xrow[h];
    #pragma unroll
    for (int e=0;e<NE;++e) acc[e] += xv * (double)sW[h*NE+e];
  }
  #pragma unroll
  for (int off=32; off>0; off>>=1){
    #pragma unroll
    for (int e=0;e<NE;++e) acc[e] += __shfl_down(acc[e], off, 64);
  }
  if (lane == 0){
    double lg[NE], p[NE];
    double m = -1e300;
    #pragma unroll
    for (int e=0;e<NE;++e){ lg[e] = acc[e] + (double)br[e]; m = fmax(m, lg[e]); }
    double s = 0.0;
    #pragma unroll
    for (int e=0;e<NE;++e){ p[e] = exp(lg[e]-m); s += p[e]; }
    double inv = 1.0 / s;
    #pragma unroll
    for (int e=0;e<NE;++e) p[e] *= inv;
    int i0 = 0;
    #pragma unroll
    for (int e=1;e<NE;++e) if (p[e] > p[i0]) i0 = e;     // strict >: lowest index on tie
    int i1 = -1;
    #pragma unroll
    for (int e=0;e<NE;++e){ if (e==i0) continue; if (i1 < 0 || p[e] > p[i1]) i1 = e; }
    double d = exp(p[i1] - p[i0]);     // softmax over the two top PROBABILITIES
    float w0 = (float)(1.0 / (1.0 + d));
    float w1 = (float)(d / (1.0 + d));
    topi[t*2+0] = i0; topi[t*2+1] = i1;
    topw[t*2+0] = w0; topw[t*2+1] = w1;
    atomicAdd(&counts[i0], 1);
    atomicAdd(&counts[i1], 1);
  }
}

__global__ void k_offsets(const int* __restrict__ counts, int* __restrict__ offsets,
                          int* __restrict__ cursor){
  if (threadIdx.x == 0 && blockIdx.x == 0){
    int run = 0;
    for (int e=0;e<NE;++e){ offsets[e] = run; cursor[e] = run; run += counts[e]; }
  }
}

__global__ __launch_bounds__(256) void k_fill(
    const int* __restrict__ topi, const float* __restrict__ topw, int* __restrict__ cursor,
    int* __restrict__ tok_of, float* __restrict__ w_of){
  int t = blockIdx.x * 256 + threadIdx.x;
  if (t >= NT) return;
  #pragma unroll
  for (int k=0;k<2;++k){
    int e = topi[t*2+k];
    int pos = atomicAdd(&cursor[e], 1);
    tok_of[pos] = t; w_of[pos] = topw[t*2+k];
  }
}

// -------- GEMM1: h = gelu(gather(x) @ W1[e] + b1[e]) --------
__global__ __launch_bounds__(256) void k_gemm1(
    const ushort* __restrict__ x, const ushort* __restrict__ w1t, const float* __restrict__ b1,
    const int* __restrict__ tok_of, const int* __restrict__ offsets, const int* __restrict__ counts,
    ushort* __restrict__ hbuf){
  int e = blockIdx.z;
  int cnt = counts[e];
  int m0 = blockIdx.y * 128;
  if (m0 >= cnt) return;
  int n0 = blockIdx.x * 128;
  int base = offsets[e];
  __shared__ __align__(16) ushort As[128][32];
  __shared__ __align__(16) ushort Bs[128][32];
  int tid = threadIdx.x;
  int r = tid >> 1, cc = (tid & 1) * 16;
  int rowv = (m0 + r) < cnt;
  int tok = rowv ? tok_of[base + m0 + r] : 0;
  const ushort* aptr = x + (size_t)tok * HID + cc;
  const ushort* bptr = w1t + (size_t)e * FF * HID + (size_t)(n0 + r) * HID + cc;
  f32x4 acc[4][4];
  #pragma unroll
  for (int i=0;i<4;++i)
    #pragma unroll
    for (int j=0;j<4;++j){ acc[i][j][0]=0.f; acc[i][j][1]=0.f; acc[i][j][2]=0.f; acc[i][j][3]=0.f; }
  int wave = tid >> 6, lane = tid & 63;
  int wr = (wave >> 1) * 64, wc = (wave & 1) * 64;
  int lrow = lane & 15, quad = lane >> 4;
  for (int kk = 0; kk < HID; kk += 32){
    uint4 a0 = *(const uint4*)(aptr + kk);
    uint4 a1 = *(const uint4*)(aptr + kk + 8);
    uint4 bb0 = *(const uint4*)(bptr + kk);
    uint4 bb1 = *(const uint4*)(bptr + kk + 8);
    *(uint4*)&As[r][cc] = a0; *(uint4*)&As[r][cc+8] = a1;
    *(uint4*)&Bs[r][cc] = bb0; *(uint4*)&Bs[r][cc+8] = bb1;
    __syncthreads();
    bf16x8 af[4], bfr[4];
    #pragma unroll
    for (int i=0;i<4;++i) af[i]  = *(const bf16x8*)&As[wr + i*16 + lrow][quad*8];
    #pragma unroll
    for (int j=0;j<4;++j) bfr[j] = *(const bf16x8*)&Bs[wc + j*16 + lrow][quad*8];
    #pragma unroll
    for (int i=0;i<4;++i)
      #pragma unroll
      for (int j=0;j<4;++j)
        acc[i][j] = __builtin_amdgcn_mfma_f32_16x16x32_bf16(af[i], bfr[j], acc[i][j], 0, 0, 0);
    __syncthreads();
  }
  #pragma unroll
  for (int i=0;i<4;++i){
    #pragma unroll
    for (int rr=0; rr<4; ++rr){
      int mrel = wr + i*16 + quad*4 + rr;   // C/D: row=(lane>>4)*4+reg, col=lane&15
      if (m0 + mrel < cnt){
        size_t grow = (size_t)(base + m0 + mrel) * FF;
        #pragma unroll
        for (int j=0;j<4;++j){
          int n = n0 + wc + j*16 + lrow;
          float v = acc[i][j][rr] + b1[e*FF + n];
          float g = 0.5f * v * (1.0f + erff(v * 0.70710678118654752f));
          hbuf[grow + n] = f2b(g);
        }
      }
    }
  }
}

// -------- GEMM2: out[tok] += w * (h @ W2[e] + b2[e])  (fp32 atomic accumulate) --------
__global__ __launch_bounds__(256) void k_gemm2(
    const ushort* __restrict__ hbuf, const ushort* __restrict__ w2t, const float* __restrict__ b2,
    const int* __restrict__ tok_of, const float* __restrict__ w_of,
    const int* __restrict__ offsets, const int* __restrict__ counts,
    float* __restrict__ outp){
  int e = blockIdx.z;
  int cnt = counts[e];
  int m0 = blockIdx.y * 128;
  if (m0 >= cnt) return;
  int n0 = blockIdx.x * 128;
  int base = offsets[e];
  __shared__ __align__(16) ushort As[128][32];
  __shared__ __align__(16) ushort Bs[128][32];
  int tid = threadIdx.x;
  int r = tid >> 1, cc = (tid & 1) * 16;
  int rowv = (m0 + r) < cnt;
  int arow = base + (rowv ? (m0 + r) : 0);
  const ushort* aptr = hbuf + (size_t)arow * FF + cc;
  const ushort* bptr = w2t + (size_t)e * HID * FF + (size_t)(n0 + r) * FF + cc;
  f32x4 acc[4][4];
  #pragma unroll
  for (int i=0;i<4;++i)
    #pragma unroll
    for (int j=0;j<4;++j){ acc[i][j][0]=0.f; acc[i][j][1]=0.f; acc[i][j][2]=0.f; acc[i][j][3]=0.f; }
  int wave = tid >> 6, lane = tid & 63;
  int wr = (wave >> 1) * 64, wc = (wave & 1) * 64;
  int lrow = lane & 15, quad = lane >> 4;
  for (int kk = 0; kk < FF; kk += 32){
    uint4 a0 = *(const uint4*)(aptr + kk);
    uint4 a1 = *(const uint4*)(aptr + kk + 8);
    uint4 bb0 = *(const uint4*)(bptr + kk);
    uint4 bb1 = *(const uint4*)(bptr + kk + 8);
    *(uint4*)&As[r][cc] = a0; *(uint4*)&As[r][cc+8] = a1;
    *(uint4*)&Bs[r][cc] = bb0; *(uint4*)&Bs[r][cc+8] = bb1;
    __syncthreads();
    bf16x8 af[4], bfr[4];
    #pragma unroll
    for (int i=0;i<4;++i) af[i]  = *(const bf16x8*)&As[wr + i*16 + lrow][quad*8];
    #pragma unroll
    for (int j=0;j<4;++j) bfr[j] = *(const bf16x8*)&Bs[wc + j*16 + lrow][quad*8];
    #pragma unroll
    for (int i=0;i<4;++i)
      #pragma unroll
      for (int j=0;j<4;++j)
        acc[i][j] = __builtin_amdgcn_mfma_f32_16x16x32_bf16(af[i], bfr[j], acc[i][j], 0, 0, 0);
    __syncthreads();
  }
  #pragma unroll
  for (int i=0;i<4;++i){
    #pragma unroll
    for (int rr=0; rr<4; ++rr){
      int mrel = wr + i*16 + quad*4 + rr;
      if (m0 + mrel < cnt){
        int pos = base + m0 + mrel;
        int tok = tok_of[pos];
        float wgt = w_of[pos];
        float* orow = outp + (size_t)tok * HID;
        #pragma unroll
        for (int j=0;j<4;++j){
          int n = n0 + wc + j*16 + lrow;
          float y = acc[i][j][rr] + b2[e*HID + n];
          atomicAdd(&orow[n], wgt * y);
        }
      }
    }
  }
}

extern "C" void kernel_launch(void* const* d_in, const int* in_sizes, int n_in,
                              void* d_out, int out_size, void* d_ws, size_t ws_size,
                              hipStream_t stream) {
  const float* x  = (const float*)d_in[0];   // [4,2048,1024]
  const float* Wr = (const float*)d_in[1];   // [1024,8]
  const float* br = (const float*)d_in[2];   // [8]
  const float* W1 = (const float*)d_in[3];   // [8,1024,2048]
  const float* b1 = (const float*)d_in[4];   // [8,2048]
  const float* W2 = (const float*)d_in[5];   // [8,2048,1024]
  const float* b2 = (const float*)d_in[6];   // [8,1024]
  float* out = (float*)d_out;                // [4,2048,1024] fp32

  char* w = (char*)d_ws;
  int*   counts  = (int*)(w + 0);
  int*   cursor  = (int*)(w + 64);
  int*   offsets = (int*)(w + 128);
  int*   topi    = (int*)(w + 131072);
  float* topw    = (float*)(w + 196608);
  int*   tok_of  = (int*)(w + 262144);
  float* w_of    = (float*)(w + 327680);
  const size_t XB_OFF  = 524288ull;
  const size_t W1T_OFF = XB_OFF  + 16ull*1024*1024;
  const size_t W2T_OFF = W1T_OFF + 32ull*1024*1024;
  const size_t HB_OFF  = W2T_OFF + 32ull*1024*1024;   // end = 150.5 MiB
  ushort* xb   = (ushort*)(w + XB_OFF);
  ushort* W1t  = (ushort*)(w + W1T_OFF);
  ushort* W2t  = (ushort*)(w + W2T_OFF);
  ushort* hbuf = (ushort*)(w + HB_OFF);

  hipMemsetAsync(w, 0, 256, stream);                          // counts + cursor
  hipMemsetAsync(out, 0, (size_t)NT*HID*sizeof(float), stream); // gemm2 accumulates into out

  k_cvt_x<<<4096, 256, 0, stream>>>(x, xb);
  k_transpose<<<dim3(FF/64, HID/64, NE), 256, 0, stream>>>(W1, W1t, HID, FF);
  k_transpose<<<dim3(HID/64, FF/64, NE), 256, 0, stream>>>(W2, W2t, FF, HID);

  k_router<<<NT/4, 256, 0, stream>>>(x, Wr, br, topi, topw, counts);
  k_offsets<<<1, 64, 0, stream>>>(counts, offsets, cursor);
  k_fill<<<NT/256, 256, 0, stream>>>(topi, topw, cursor, tok_of, w_of);

  k_gemm1<<<dim3(FF/128, NT/128, NE), 256, 0, stream>>>(xb, W1t, b1, tok_of, offsets, counts, hbuf);
  k_gemm2<<<dim3(HID/128, NT/128, NE), 256, 0, stream>>>(hbuf, W2t, b2, tok_of, w_of, offsets, counts, out);
}

// Round 4
// 552.406 us; speedup vs baseline: 1.4887x; 1.4887x over previous
//
#include <hip/hip_runtime.h>
#include <math.h>

#define HID 1024
#define FF  2048
#define NE  8
#define NT  8192

typedef __attribute__((ext_vector_type(4))) float f32x4;
typedef __bf16 bf16x8 __attribute__((ext_vector_type(8)));

// async global->LDS DMA, 16B per lane, dest = wave-uniform base + lane*16
#define GLL(g, l) __builtin_amdgcn_global_load_lds( \
    (const __attribute__((address_space(1))) unsigned int*)(g), \
    (__attribute__((address_space(3))) unsigned int*)(l), 16, 0, 0)

static __device__ __forceinline__ ushort f2b(float f){
  union { float f; unsigned int u; } v; v.f = f;
  unsigned int r = (v.u + 0x7FFFu + ((v.u >> 16) & 1u)) >> 16;
  return (ushort)r;
}

// -------- x (fp32) -> bf16 xb --------
__global__ __launch_bounds__(256) void k_cvt_x(const float* __restrict__ x,
                                               ushort* __restrict__ xb){
  size_t i8 = ((size_t)blockIdx.x * 256 + threadIdx.x) * 8;
  const float* s = x + i8;
  ushort o[8];
  #pragma unroll
  for (int j = 0; j < 8; ++j) o[j] = f2b(s[j]);
  *(uint4*)(xb + i8) = *(uint4*)o;
}

// -------- 64x64 tile transpose + fp32->bf16: src[e][K][N] -> dst[e][N][K] --------
__global__ __launch_bounds__(256) void k_transpose(
    const float* __restrict__ src, ushort* __restrict__ dst, int K, int N){
  __shared__ __align__(16) ushort Tt[64][72];
  int e = blockIdx.z;
  int n0 = blockIdx.x * 64, k0 = blockIdx.y * 64;
  int t = threadIdx.x;
  int r = t >> 2, c = (t & 3) * 16;
  const float* s = src + (size_t)e*K*N + (size_t)(k0+r)*N + n0 + c;
  #pragma unroll
  for (int q = 0; q < 4; ++q){
    float4 v = *(const float4*)(s + q*4);
    Tt[r][c+q*4+0] = f2b(v.x); Tt[r][c+q*4+1] = f2b(v.y);
    Tt[r][c+q*4+2] = f2b(v.z); Tt[r][c+q*4+3] = f2b(v.w);
  }
  __syncthreads();
  ushort tmp[16];
  #pragma unroll
  for (int i = 0; i < 16; ++i) tmp[i] = Tt[c+i][r];
  ushort* d = dst + (size_t)e*N*K + (size_t)(n0+r)*K + k0 + c;
  *(uint4*)(d)     = *(uint4*)&tmp[0];
  *(uint4*)(d + 8) = *(uint4*)&tmp[8];
}

// -------- Router (fp32 inputs, fp64 accumulation) --------
__global__ __launch_bounds__(256) void k_router(
    const float* __restrict__ x, const float* __restrict__ Wr,
    const float* __restrict__ br, int* __restrict__ topi,
    float* __restrict__ topw){
  __shared__ __align__(16) float sW[HID*NE];   // 32 KB
  int tid = threadIdx.x;
  const uint4* srcW = (const uint4*)Wr;
  uint4* dstW = (uint4*)sW;
  #pragma unroll
  for (int i = 0; i < 8; ++i) dstW[tid*8+i] = srcW[tid*8+i];
  __syncthreads();
  int wave = tid >> 6, lane = tid & 63;
  int t = blockIdx.x * 4 + wave;
  const float* xrow = x + (size_t)t * HID;
  double acc[NE];
  #pragma unroll
  for (int e=0;e<NE;++e) acc[e]=0.0;
  for (int it = 0; it < HID/64; ++it){
    int h = it*64 + lane;
    double xv = (double)xrow[h];
    #pragma unroll
    for (int e=0;e<NE;++e) acc[e] += xv * (double)sW[h*NE+e];
  }
  #pragma unroll
  for (int off=32; off>0; off>>=1){
    #pragma unroll
    for (int e=0;e<NE;++e) acc[e] += __shfl_down(acc[e], off, 64);
  }
  if (lane == 0){
    double lg[NE], p[NE];
    double m = -1e300;
    #pragma unroll
    for (int e=0;e<NE;++e){ lg[e] = acc[e] + (double)br[e]; m = fmax(m, lg[e]); }
    double s = 0.0;
    #pragma unroll
    for (int e=0;e<NE;++e){ p[e] = exp(lg[e]-m); s += p[e]; }
    double inv = 1.0 / s;
    #pragma unroll
    for (int e=0;e<NE;++e) p[e] *= inv;
    int i0 = 0;
    #pragma unroll
    for (int e=1;e<NE;++e) if (p[e] > p[i0]) i0 = e;     // strict >: lowest index on tie
    int i1 = -1;
    #pragma unroll
    for (int e=0;e<NE;++e){ if (e==i0) continue; if (i1 < 0 || p[e] > p[i1]) i1 = e; }
    double d = exp(p[i1] - p[i0]);     // softmax over the two top PROBABILITIES
    topi[t*2+0] = i0; topi[t*2+1] = i1;
    topw[t*2+0] = (float)(1.0 / (1.0 + d));
    topw[t*2+1] = (float)(d / (1.0 + d));
  }
}

// -------- per-block aggregated count --------
__global__ __launch_bounds__(256) void k_count(
    const int* __restrict__ topi, int* __restrict__ counts){
  __shared__ int lcnt[NE];
  int tid = threadIdx.x;
  if (tid < NE) lcnt[tid] = 0;
  __syncthreads();
  int t = blockIdx.x * 256 + tid;
  atomicAdd(&lcnt[topi[t*2+0]], 1);
  atomicAdd(&lcnt[topi[t*2+1]], 1);
  __syncthreads();
  if (tid < NE) atomicAdd(&counts[tid], lcnt[tid]);
}

__global__ void k_offsets(const int* __restrict__ counts, int* __restrict__ offsets,
                          int* __restrict__ cursor){
  if (threadIdx.x == 0 && blockIdx.x == 0){
    int run = 0;
    for (int e=0;e<NE;++e){ offsets[e] = run; cursor[e] = run; run += counts[e]; }
  }
}

// -------- per-block aggregated fill (256 global atomics total) --------
__global__ __launch_bounds__(256) void k_fill(
    const int* __restrict__ topi, const float* __restrict__ topw, int* __restrict__ cursor,
    int* __restrict__ tok_of, float* __restrict__ w_of){
  __shared__ int lcnt[NE];
  __shared__ int lbase[NE];
  int tid = threadIdx.x;
  if (tid < NE) lcnt[tid] = 0;
  __syncthreads();
  int t = blockIdx.x * 256 + tid;
  int e0 = topi[t*2+0], e1 = topi[t*2+1];
  int p0 = atomicAdd(&lcnt[e0], 1);
  int p1 = atomicAdd(&lcnt[e1], 1);
  __syncthreads();
  if (tid < NE) lbase[tid] = atomicAdd(&cursor[tid], lcnt[tid]);
  __syncthreads();
  int pos0 = lbase[e0] + p0;
  tok_of[pos0] = t; w_of[pos0] = topw[t*2+0];
  int pos1 = lbase[e1] + p1;
  tok_of[pos1] = t; w_of[pos1] = topw[t*2+1];
}

// -------- GEMM1: h = gelu(gather(x) @ W1[e] + b1[e]), async LDS staging --------
__global__ __launch_bounds__(256) void k_gemm1(
    const ushort* __restrict__ x, const ushort* __restrict__ w1t, const float* __restrict__ b1,
    const int* __restrict__ tok_of, const int* __restrict__ offsets, const int* __restrict__ counts,
    ushort* __restrict__ hbuf){
  int e = blockIdx.z;
  int cnt = counts[e];
  int m0 = blockIdx.y * 128;
  if (m0 >= cnt) return;
  int n0 = blockIdx.x * 128;
  int base = offsets[e];
  __shared__ __align__(16) ushort As[128][32];
  __shared__ __align__(16) ushort Bs[128][32];
  int tid = threadIdx.x;
  int wave = tid >> 6, lane = tid & 63;
  // staging: wave w covers rows [w*32, w*32+32); 2 DMA instrs of 16 rows each
  int srow0 = wave*32 + (lane >> 2);
  int srow1 = srow0 + 16;
  int chunk = (lane & 3) * 8;                    // ushort offset (16B chunks)
  int t0 = tok_of[base + min(m0 + srow0, cnt-1)];
  int t1 = tok_of[base + min(m0 + srow1, cnt-1)];
  const ushort* agp0 = x + (size_t)t0*HID + chunk;
  const ushort* agp1 = x + (size_t)t1*HID + chunk;
  const ushort* wb = w1t + (size_t)e*FF*HID;
  const ushort* bgp0 = wb + (size_t)(n0 + srow0)*HID + chunk;
  const ushort* bgp1 = wb + (size_t)(n0 + srow1)*HID + chunk;
  ushort* alds0 = &As[wave*32][0];
  ushort* alds1 = &As[wave*32+16][0];
  ushort* blds0 = &Bs[wave*32][0];
  ushort* blds1 = &Bs[wave*32+16][0];
  f32x4 acc[4][4];
  #pragma unroll
  for (int i=0;i<4;++i)
    #pragma unroll
    for (int j=0;j<4;++j){ acc[i][j][0]=0.f; acc[i][j][1]=0.f; acc[i][j][2]=0.f; acc[i][j][3]=0.f; }
  int wr = (wave >> 1) * 64, wc = (wave & 1) * 64;
  int lrow = lane & 15, quad = lane >> 4;
  for (int kk = 0; kk < HID; kk += 32){
    GLL(agp0 + kk, alds0);
    GLL(agp1 + kk, alds1);
    GLL(bgp0 + kk, blds0);
    GLL(bgp1 + kk, blds1);
    __syncthreads();                 // drains vmcnt before barrier
    bf16x8 af[4], bfr[4];
    #pragma unroll
    for (int i=0;i<4;++i) af[i]  = *(const bf16x8*)&As[wr + i*16 + lrow][quad*8];
    #pragma unroll
    for (int j=0;j<4;++j) bfr[j] = *(const bf16x8*)&Bs[wc + j*16 + lrow][quad*8];
    #pragma unroll
    for (int i=0;i<4;++i)
      #pragma unroll
      for (int j=0;j<4;++j)
        acc[i][j] = __builtin_amdgcn_mfma_f32_16x16x32_bf16(af[i], bfr[j], acc[i][j], 0, 0, 0);
    __syncthreads();
  }
  #pragma unroll
  for (int i=0;i<4;++i){
    #pragma unroll
    for (int rr=0; rr<4; ++rr){
      int mrel = wr + i*16 + quad*4 + rr;   // C/D: row=(lane>>4)*4+reg, col=lane&15
      if (m0 + mrel < cnt){
        size_t grow = (size_t)(base + m0 + mrel) * FF;
        #pragma unroll
        for (int j=0;j<4;++j){
          int n = n0 + wc + j*16 + lrow;
          float v = acc[i][j][rr] + b1[e*FF + n];
          float g = 0.5f * v * (1.0f + erff(v * 0.70710678118654752f));
          hbuf[grow + n] = f2b(g);
        }
      }
    }
  }
}

// -------- GEMM2: out[tok] += w * (h @ W2[e] + b2[e]), async LDS staging --------
__global__ __launch_bounds__(256) void k_gemm2(
    const ushort* __restrict__ hbuf, const ushort* __restrict__ w2t, const float* __restrict__ b2,
    const int* __restrict__ tok_of, const float* __restrict__ w_of,
    const int* __restrict__ offsets, const int* __restrict__ counts,
    float* __restrict__ outp){
  int e = blockIdx.z;
  int cnt = counts[e];
  int m0 = blockIdx.y * 128;
  if (m0 >= cnt) return;
  int n0 = blockIdx.x * 128;
  int base = offsets[e];
  __shared__ __align__(16) ushort As[128][32];
  __shared__ __align__(16) ushort Bs[128][32];
  int tid = threadIdx.x;
  int wave = tid >> 6, lane = tid & 63;
  int srow0 = wave*32 + (lane >> 2);
  int srow1 = srow0 + 16;
  int chunk = (lane & 3) * 8;
  int ar0 = base + min(m0 + srow0, cnt-1);
  int ar1 = base + min(m0 + srow1, cnt-1);
  const ushort* agp0 = hbuf + (size_t)ar0*FF + chunk;
  const ushort* agp1 = hbuf + (size_t)ar1*FF + chunk;
  const ushort* wb = w2t + (size_t)e*HID*FF;
  const ushort* bgp0 = wb + (size_t)(n0 + srow0)*FF + chunk;
  const ushort* bgp1 = wb + (size_t)(n0 + srow1)*FF + chunk;
  ushort* alds0 = &As[wave*32][0];
  ushort* alds1 = &As[wave*32+16][0];
  ushort* blds0 = &Bs[wave*32][0];
  ushort* blds1 = &Bs[wave*32+16][0];
  f32x4 acc[4][4];
  #pragma unroll
  for (int i=0;i<4;++i)
    #pragma unroll
    for (int j=0;j<4;++j){ acc[i][j][0]=0.f; acc[i][j][1]=0.f; acc[i][j][2]=0.f; acc[i][j][3]=0.f; }
  int wr = (wave >> 1) * 64, wc = (wave & 1) * 64;
  int lrow = lane & 15, quad = lane >> 4;
  for (int kk = 0; kk < FF; kk += 32){
    GLL(agp0 + kk, alds0);
    GLL(agp1 + kk, alds1);
    GLL(bgp0 + kk, blds0);
    GLL(bgp1 + kk, blds1);
    __syncthreads();
    bf16x8 af[4], bfr[4];
    #pragma unroll
    for (int i=0;i<4;++i) af[i]  = *(const bf16x8*)&As[wr + i*16 + lrow][quad*8];
    #pragma unroll
    for (int j=0;j<4;++j) bfr[j] = *(const bf16x8*)&Bs[wc + j*16 + lrow][quad*8];
    #pragma unroll
    for (int i=0;i<4;++i)
      #pragma unroll
      for (int j=0;j<4;++j)
        acc[i][j] = __builtin_amdgcn_mfma_f32_16x16x32_bf16(af[i], bfr[j], acc[i][j], 0, 0, 0);
    __syncthreads();
  }
  #pragma unroll
  for (int i=0;i<4;++i){
    #pragma unroll
    for (int rr=0; rr<4; ++rr){
      int mrel = wr + i*16 + quad*4 + rr;
      if (m0 + mrel < cnt){
        int pos = base + m0 + mrel;
        int tok = tok_of[pos];
        float wgt = w_of[pos];
        float* orow = outp + (size_t)tok * HID;
        #pragma unroll
        for (int j=0;j<4;++j){
          int n = n0 + wc + j*16 + lrow;
          float y = acc[i][j][rr] + b2[e*HID + n];
          atomicAdd(&orow[n], wgt * y);
        }
      }
    }
  }
}

extern "C" void kernel_launch(void* const* d_in, const int* in_sizes, int n_in,
                              void* d_out, int out_size, void* d_ws, size_t ws_size,
                              hipStream_t stream) {
  const float* x  = (const float*)d_in[0];   // [4,2048,1024]
  const float* Wr = (const float*)d_in[1];   // [1024,8]
  const float* br = (const float*)d_in[2];   // [8]
  const float* W1 = (const float*)d_in[3];   // [8,1024,2048]
  const float* b1 = (const float*)d_in[4];   // [8,2048]
  const float* W2 = (const float*)d_in[5];   // [8,2048,1024]
  const float* b2 = (const float*)d_in[6];   // [8,1024]
  float* out = (float*)d_out;                // [4,2048,1024] fp32

  char* w = (char*)d_ws;
  int*   counts  = (int*)(w + 0);
  int*   cursor  = (int*)(w + 64);
  int*   offsets = (int*)(w + 128);
  int*   topi    = (int*)(w + 131072);
  float* topw    = (float*)(w + 196608);
  int*   tok_of  = (int*)(w + 262144);
  float* w_of    = (float*)(w + 327680);
  const size_t XB_OFF  = 524288ull;
  const size_t W1T_OFF = XB_OFF  + 16ull*1024*1024;
  const size_t W2T_OFF = W1T_OFF + 32ull*1024*1024;
  const size_t HB_OFF  = W2T_OFF + 32ull*1024*1024;   // end = 150.5 MiB
  ushort* xb   = (ushort*)(w + XB_OFF);
  ushort* W1t  = (ushort*)(w + W1T_OFF);
  ushort* W2t  = (ushort*)(w + W2T_OFF);
  ushort* hbuf = (ushort*)(w + HB_OFF);

  hipMemsetAsync(w, 0, 256, stream);                            // counts + cursor
  hipMemsetAsync(out, 0, (size_t)NT*HID*sizeof(float), stream); // gemm2 accumulates into out

  k_cvt_x<<<4096, 256, 0, stream>>>(x, xb);
  k_transpose<<<dim3(FF/64, HID/64, NE), 256, 0, stream>>>(W1, W1t, HID, FF);
  k_transpose<<<dim3(HID/64, FF/64, NE), 256, 0, stream>>>(W2, W2t, FF, HID);

  k_router<<<NT/4, 256, 0, stream>>>(x, Wr, br, topi, topw);
  k_count<<<NT/256, 256, 0, stream>>>(topi, counts);
  k_offsets<<<1, 64, 0, stream>>>(counts, offsets, cursor);
  k_fill<<<NT/256, 256, 0, stream>>>(topi, topw, cursor, tok_of, w_of);

  k_gemm1<<<dim3(FF/128, NT/128, NE), 256, 0, stream>>>(xb, W1t, b1, tok_of, offsets, counts, hbuf);
  k_gemm2<<<dim3(HID/128, NT/128, NE), 256, 0, stream>>>(hbuf, W2t, b2, tok_of, w_of, offsets, counts, out);
}